// Round 3
// baseline (173.036 us; speedup 1.0000x reference)
//
#include <hip/hip_runtime.h>
#include <math.h>

// Marching tets, fully analytic grid, 2 kernels + 1 memset:
//  K1 (vertex-partition): occupancy bits, crossing-edge flags, decoupled-lookback
//     scan of (edgeCnt, t1, t2) block aggregates, emits interpolated verts +
//     SoA edgeRank planes. Last block publishes totals {M, N1, N2}.
//  K2 (tet-per-thread, 6x parallelism): own decoupled lookback (with prefix
//     short-circuit) for 1-tri/2-tri ranks, gathers edgeRank, emits faces.
// Lookback relies on (a) K1 grid fully co-resident (1073 blocks < capacity),
// (b) AMD CP in-order-ish dispatch for K2 (standard rocPRIM assumption).

typedef unsigned long long ull;

#define ST_LD(p)    __hip_atomic_load((p), __ATOMIC_RELAXED, __HIP_MEMORY_SCOPE_AGENT)
#define ST_ST(p,v)  __hip_atomic_store((p), (v), __ATOMIC_RELAXED, __HIP_MEMORY_SCOPE_AGENT)

__device__ __constant__ int c_tri_tab[16][6] = {
    {-1,-1,-1,-1,-1,-1},{1,0,2,-1,-1,-1},{4,0,3,-1,-1,-1},{1,4,2,1,3,4},
    {3,1,5,-1,-1,-1},{2,3,0,2,5,3},{1,4,0,1,5,4},{4,2,5,-1,-1,-1},
    {4,5,2,-1,-1,-1},{4,1,0,4,5,1},{3,2,0,3,5,2},{1,3,5,-1,-1,-1},
    {4,1,2,4,3,1},{3,0,4,-1,-1,-1},{2,0,1,-1,-1,-1},{-1,-1,-1,-1,-1,-1}};
__device__ __constant__ int c_num_tri[16] = {0,1,1,2,1,2,2,1,1,2,2,1,2,1,1,0};
// 6-tet decomposition: cube-corner tuples (corner c = dx<<2|dy<<1|dz)
__device__ __constant__ int c_tc[6][4] = {{0,1,3,7},{0,3,2,7},{0,2,6,7},{0,6,4,7},{0,4,5,7},{0,5,1,7}};
// per (tet k, local edge le): (cmin_corner<<3) | offset_slot_j
__device__ __constant__ int c_te[6][6] = {
    {(0<<3)|0,(0<<3)|2,(0<<3)|6,(1<<3)|1,(1<<3)|5,(3<<3)|3},
    {(0<<3)|2,(0<<3)|1,(0<<3)|6,(2<<3)|0,(3<<3)|3,(2<<3)|4},
    {(0<<3)|1,(0<<3)|5,(0<<3)|6,(2<<3)|3,(2<<3)|4,(6<<3)|0},
    {(0<<3)|5,(0<<3)|3,(0<<3)|6,(4<<3)|1,(6<<3)|0,(4<<3)|2},
    {(0<<3)|3,(0<<3)|4,(0<<3)|6,(4<<3)|0,(4<<3)|2,(5<<3)|1},
    {(0<<3)|4,(0<<3)|0,(0<<3)|6,(1<<3)|3,(5<<3)|1,(1<<3)|5}};

__device__ __forceinline__ int occ_bit(const ull* __restrict__ occ64, int id) {
    return (int)((occ64[id >> 6] >> (id & 63)) & 1ull);
}

// K1: count + lookback-scan + vertex/edgeRank emit. State word:
// [flag:1 | e:21 | t1:21 | t2:21]  (all grand totals < 2^21, packed adds safe)
__global__ void k_vert(const float* __restrict__ level, const float* __restrict__ deform,
                       int NV, int r1, float invR,
                       ull* __restrict__ occ64, ull* __restrict__ stateV,
                       int* __restrict__ edgeRank, int* __restrict__ totals,
                       float* __restrict__ out) {
    int b = blockIdx.x;
    int v = b * 256 + threadIdx.x;
    int R = r1 - 1, rsq = r1 * r1;
    bool valid = v < NV;
    float la = valid ? level[v] : 0.f;
    bool occv = valid && (la > 0.f);
    ull bal = __ballot(occv);
    if ((threadIdx.x & 63) == 0 && valid) occ64[v >> 6] = bal;

    int x = 0, y = 0, z = 0, flags = 0, n1 = 0, n2 = 0;
    float lb[7];
    if (valid) {
        x = v / rsq; int rem = v - x * rsq; y = rem / r1; z = rem - y * r1;
        bool bx = x < R, by = y < R, bz = z < R;
        bool inb[7] = {bz, by, by && bz, bx, bx && bz, bx && by, bx && by && bz};
        int deltas[7] = {1, r1, r1 + 1, rsq, rsq + 1, rsq + r1, rsq + r1 + 1};
        int ob = occv ? 1 : 0;
        for (int j = 0; j < 7; j++) {
            float l = inb[j] ? level[v + deltas[j]] : 0.f;
            lb[j] = l;
            bool o = inb[j] && (l > 0.f);
            ob |= (o ? 1 : 0) << (j + 1);
            if (inb[j] && (o != occv)) flags |= 1 << j;
        }
        if (bx && by && bz) {
            for (int k = 0; k < 6; k++) {
                int ti = ((ob >> c_tc[k][0]) & 1) | (((ob >> c_tc[k][1]) & 1) << 1)
                       | (((ob >> c_tc[k][2]) & 1) << 2) | (((ob >> c_tc[k][3]) & 1) << 3);
                int n = c_num_tri[ti];
                n1 += (n == 1); n2 += (n == 2);
            }
        }
    }
    int cnt = __popc(flags);
    int lane = threadIdx.x & 63, wv = threadIdx.x >> 6;
    int incl = cnt;
    for (int o = 1; o < 64; o <<= 1) { int t = __shfl_up(incl, o); if (lane >= o) incl += t; }
    int pk = n1 | (n2 << 16);
    int rsum = pk;
    for (int o = 1; o < 64; o <<= 1) rsum += __shfl_xor(rsum, o);

    __shared__ int wE[4], wT[4];
    __shared__ ull sExcl;
    if (lane == 63) wE[wv] = incl;
    if (lane == 0)  wT[wv] = rsum;
    __syncthreads();

    if (wv == 0) {
        int eb = 0, t1b = 0, t2b = 0;
        if (lane == 0) {
            eb = wE[0] + wE[1] + wE[2] + wE[3];
            int tb = wT[0] + wT[1] + wT[2] + wT[3];
            t1b = tb & 0xffff; t2b = tb >> 16;
            ST_ST(&stateV[b], (1ull << 63) | ((ull)eb << 42) | ((ull)t1b << 21) | (ull)t2b);
        }
        ull sum = 0;
        for (int w = 0; 64 * w < b; w++) {
            int i = b - 1 - 64 * w - lane;
            ull s = 0;
            if (i >= 0) { do { s = ST_LD(&stateV[i]); } while (!(s >> 63)); }
            ull val = (i >= 0) ? (s & ~(1ull << 63)) : 0;
            for (int o = 1; o < 64; o <<= 1) val += __shfl_xor(val, o);
            sum += val;
        }
        if (lane == 0) {
            sExcl = sum;
            if (b == (int)gridDim.x - 1) {
                totals[0] = (int)((sum >> 42) & 0x1FFFFF) + eb;   // M
                totals[1] = (int)((sum >> 21) & 0x1FFFFF) + t1b;  // N1
                totals[2] = (int)(sum & 0x1FFFFF) + t2b;          // N2
            }
        }
    }
    __syncthreads();

    ull ex = sExcl;
    int exclE = (int)((ex >> 42) & 0x1FFFFF);
    int woff = 0;
    for (int w = 0; w < wv; w++) woff += wE[w];
    int rank0 = exclE + woff + incl - cnt;

    if (valid) {
        int er[7]; int r = rank0;
        for (int j = 0; j < 7; j++) er[j] = ((flags >> j) & 1) ? r++ : -1;
        for (int j = 0; j < 7; j++) edgeRank[(size_t)j * NV + v] = er[j];  // SoA, coalesced
    }
    if (flags) {
        int deltas[7] = {1, r1, r1 + 1, rsq, rsq + 1, rsq + r1, rsq + r1 + 1};
        const int dxs[7] = {0, 0, 0, 1, 1, 1, 1};
        const int dys[7] = {0, 1, 1, 0, 0, 1, 1};
        const int dzs[7] = {1, 0, 1, 0, 1, 0, 1};
        float pax = x * invR + tanhf(deform[3 * v])     * invR;
        float pay = y * invR + tanhf(deform[3 * v + 1]) * invR;
        float paz = z * invR + tanhf(deform[3 * v + 2]) * invR;
        int r = rank0;
        for (int j = 0; j < 7; j++) {
            if (!((flags >> j) & 1)) continue;
            int bb = v + deltas[j];
            float lbv = lb[j];
            float denom = la - lbv;
            float w0 = (-lbv) / denom;
            float w1f = la / denom;
            float pbx = (x + dxs[j]) * invR + tanhf(deform[3 * bb])     * invR;
            float pby = (y + dys[j]) * invR + tanhf(deform[3 * bb + 1]) * invR;
            float pbz = (z + dzs[j]) * invR + tanhf(deform[3 * bb + 2]) * invR;
            out[3 * r]     = pax * w0 + pbx * w1f;
            out[3 * r + 1] = pay * w0 + pby * w1f;
            out[3 * r + 2] = paz * w0 + pbz * w1f;
            r++;
        }
    }
}

// K2: tet-per-thread. State word: [st:2 | t1incl_or_agg:31 | t2:31], st 0/1(agg)/2(prefix)
__global__ void k_face(int NV, int r1, int NT,
                       const ull* __restrict__ occ64, ull* __restrict__ stateT,
                       const int* __restrict__ edgeRank, const int* __restrict__ totals,
                       float* __restrict__ out) {
    int b = blockIdx.x;
    int t = b * 256 + threadIdx.x;
    int R = r1 - 1, rsq = r1 * r1;
    int nt = 0, ti = 0, k = 0, v = 0;
    if (t < NT) {
        int c = t / 6; k = t - c * 6;
        int rr = R * R;
        int cx = c / rr; int rem = c - cx * rr; int cy = rem / R; int cz = rem - cy * R;
        v = (cx * r1 + cy) * r1 + cz;
        int off0 = 0, off1 = 1, off2 = r1, off3 = r1 + 1, off4 = rsq, off5 = rsq + 1, off6 = rsq + r1, off7 = rsq + r1 + 1;
        int off[8] = {off0, off1, off2, off3, off4, off5, off6, off7};
        ti = occ_bit(occ64, v + off[c_tc[k][0]])
           | (occ_bit(occ64, v + off[c_tc[k][1]]) << 1)
           | (occ_bit(occ64, v + off[c_tc[k][2]]) << 2)
           | (occ_bit(occ64, v + off[c_tc[k][3]]) << 3);
        nt = c_num_tri[ti];
    }
    ull m1 = __ballot(nt == 1);
    ull m2 = __ballot(nt == 2);
    int lane = threadIdx.x & 63, wv = threadIdx.x >> 6;
    ull ltm = (1ull << lane) - 1ull;
    int p1 = __popcll(m1 & ltm);
    int p2 = __popcll(m2 & ltm);
    __shared__ int w1[4], w2[4];
    __shared__ ull sE;
    if (lane == 0) { w1[wv] = __popcll(m1); w2[wv] = __popcll(m2); }
    __syncthreads();

    if (wv == 0) {
        int t1b = 0, t2b = 0;
        if (lane == 0) {
            t1b = w1[0] + w1[1] + w1[2] + w1[3];
            t2b = w2[0] + w2[1] + w2[2] + w2[3];
            ST_ST(&stateT[b], (1ull << 62) | ((ull)t1b << 31) | (ull)t2b);
        }
        const ull VMASK = (1ull << 62) - 1ull;
        ull sum = 0;
        for (int w = 0; 64 * w < b; w++) {
            int i = b - 1 - 64 * w - lane;
            ull s = 0;
            if (i >= 0) { do { s = ST_LD(&stateT[i]); } while (!(s >> 62)); }
            unsigned st = (unsigned)(s >> 62);
            ull pm = __ballot(st == 2u && i >= 0);
            int Lp = pm ? (__ffsll(pm) - 1) : 64;
            ull val = (i >= 0 && lane <= Lp) ? (s & VMASK) : 0;
            for (int o = 1; o < 64; o <<= 1) val += __shfl_xor(val, o);
            sum += val;
            if (Lp < 64) break;
        }
        if (lane == 0) {
            sE = sum;
            ull inc1 = ((sum >> 31) & 0x7FFFFFFFull) + (ull)t1b;
            ull inc2 = (sum & 0x7FFFFFFFull) + (ull)t2b;
            ST_ST(&stateT[b], (2ull << 62) | (inc1 << 31) | inc2);
        }
    }
    __syncthreads();

    if (nt == 0) return;
    ull ex = sE;
    int excl1 = (int)((ex >> 31) & 0x7FFFFFFF);
    int excl2 = (int)(ex & 0x7FFFFFFF);
    int o1 = 0, o2 = 0;
    for (int w = 0; w < wv; w++) { o1 += w1[w]; o2 += w2[w]; }

    int M = totals[0], N1 = totals[1];
    float* faces = out + 3 * (size_t)M;
    int off[8] = {0, 1, r1, r1 + 1, rsq, rsq + 1, rsq + r1, rsq + r1 + 1};
    float vals[6];
    int ne = nt * 3;
    for (int e = 0; e < ne; e++) {
        int le = c_tri_tab[ti][e];
        int ce = c_te[k][le];
        int a = v + off[ce >> 3];
        vals[e] = (float)edgeRank[(size_t)(ce & 7) * NV + a];
    }
    if (nt == 1) {
        size_t base = 3 * (size_t)(excl1 + o1 + p1);
        faces[base] = vals[0]; faces[base + 1] = vals[1]; faces[base + 2] = vals[2];
    } else {
        size_t base = 3 * ((size_t)N1 + 2 * (size_t)(excl2 + o2 + p2));
        for (int e = 0; e < 6; e++) faces[base + e] = vals[e];
    }
}

extern "C" void kernel_launch(void* const* d_in, const int* in_sizes, int n_in,
                              void* d_out, int out_size, void* d_ws, size_t ws_size,
                              hipStream_t stream) {
    const float* level  = (const float*)d_in[0];
    const float* deform = (const float*)d_in[1];
    int NV = in_sizes[0];
    int r1 = 1;
    while ((long long)r1 * r1 * r1 < (long long)NV) r1++;
    int R = r1 - 1;
    float invR = 1.0f / (float)R;

    int nb = (NV + 255) / 256;
    int nw = (NV + 63) / 64;
    long long NTl = 6LL * R * R * R;
    int NT = (int)NTl;
    int nbT = (NT + 255) / 256;

    char* w = (char*)d_ws;
    int* edgeRank = (int*)w;
    w += (((size_t)NV * 7 * sizeof(int)) + 255) & ~(size_t)255;
    ull* occ64 = (ull*)w;
    w += (((size_t)nw * 8) + 255) & ~(size_t)255;
    ull* stateV = (ull*)w;
    ull* stateT = stateV + nb;
    int* totals = (int*)(stateT + nbT);
    size_t zbytes = (size_t)(nb + nbT) * 8 + 4 * sizeof(int);

    float* out = (float*)d_out;

    hipMemsetAsync(stateV, 0, zbytes, stream);
    k_vert<<<nb, 256, 0, stream>>>(level, deform, NV, r1, invR, occ64, stateV, edgeRank, totals, out);
    k_face<<<nbT, 256, 0, stream>>>(NV, r1, NT, occ64, stateT, edgeRank, totals, out);
}

// Round 5
// 136.917 us; speedup vs baseline: 1.2638x; 1.2638x over previous
//
#include <hip/hip_runtime.h>
#include <math.h>

// Marching tets, fully analytic grid, 2 kernels + 1 memset:
//  K1 (vertex partition, 1073 blocks): occupancy bits, crossing-edge flags,
//     decoupled-lookback scan WITH prefix short-circuit (two state arrays) of
//     (edgeCnt, t1, t2), emits interpolated verts + SoA edgeRank planes,
//     plus per-cube obByte (8-bit cube occ mask) and cubeRank (exclusive
//     global (rank1,rank2) for each cube). Last block publishes totals.
//  K2 (tet-per-thread, scan-free): class + intra-cube offset from a 256-entry
//     LDS table on obByte (64-bit entries! 36 bits used — 32-bit overflowed in R4),
//     rank = cubeRank + intra-cube prefix, gather edgeRank, coalesced writes.

typedef unsigned long long ull;

#define ST_LD(p)    __hip_atomic_load((p), __ATOMIC_RELAXED, __HIP_MEMORY_SCOPE_AGENT)
#define ST_ST(p,v)  __hip_atomic_store((p), (v), __ATOMIC_RELAXED, __HIP_MEMORY_SCOPE_AGENT)

__device__ __constant__ int c_tri_tab[16][6] = {
    {-1,-1,-1,-1,-1,-1},{1,0,2,-1,-1,-1},{4,0,3,-1,-1,-1},{1,4,2,1,3,4},
    {3,1,5,-1,-1,-1},{2,3,0,2,5,3},{1,4,0,1,5,4},{4,2,5,-1,-1,-1},
    {4,5,2,-1,-1,-1},{4,1,0,4,5,1},{3,2,0,3,5,2},{1,3,5,-1,-1,-1},
    {4,1,2,4,3,1},{3,0,4,-1,-1,-1},{2,0,1,-1,-1,-1},{-1,-1,-1,-1,-1,-1}};
__device__ __constant__ int c_num_tri[16] = {0,1,1,2,1,2,2,1,1,2,2,1,2,1,1,0};
// 6-tet decomposition: cube-corner tuples (corner c = dx<<2|dy<<1|dz)
__device__ __constant__ int c_tc[6][4] = {{0,1,3,7},{0,3,2,7},{0,2,6,7},{0,6,4,7},{0,4,5,7},{0,5,1,7}};
// per (tet k, local edge le): (cmin_corner<<3) | offset_slot_j
__device__ __constant__ int c_te[6][6] = {
    {(0<<3)|0,(0<<3)|2,(0<<3)|6,(1<<3)|1,(1<<3)|5,(3<<3)|3},
    {(0<<3)|2,(0<<3)|1,(0<<3)|6,(2<<3)|0,(3<<3)|3,(2<<3)|4},
    {(0<<3)|1,(0<<3)|5,(0<<3)|6,(2<<3)|3,(2<<3)|4,(6<<3)|0},
    {(0<<3)|5,(0<<3)|3,(0<<3)|6,(4<<3)|1,(6<<3)|0,(4<<3)|2},
    {(0<<3)|3,(0<<3)|4,(0<<3)|6,(4<<3)|0,(4<<3)|2,(5<<3)|1},
    {(0<<3)|4,(0<<3)|0,(0<<3)|6,(1<<3)|3,(5<<3)|1,(1<<3)|5}};

// value packing for scan states: [flag:1 | e:21 | t1:21 | t2:21]
#define VMASK ((1ull << 63) - 1ull)

__global__ void k_vert(const float* __restrict__ level, const float* __restrict__ deform,
                       int NV, int r1, float invR,
                       ull* __restrict__ occ64, ull* __restrict__ stateA, ull* __restrict__ prefS,
                       int* __restrict__ edgeRank, unsigned char* __restrict__ obByte,
                       uint2* __restrict__ cubeRank, int* __restrict__ totals,
                       float* __restrict__ out) {
    int b = blockIdx.x;
    int v = b * 256 + threadIdx.x;
    int R = r1 - 1, rsq = r1 * r1;
    bool valid = v < NV;
    float la = valid ? level[v] : 0.f;
    bool occv = valid && (la > 0.f);
    ull bal = __ballot(occv);
    if ((threadIdx.x & 63) == 0 && valid) occ64[v >> 6] = bal;

    int x = 0, y = 0, z = 0, flags = 0, n1 = 0, n2 = 0, cidx = 0;
    bool interior = false;
    float lb[7];
    if (valid) {
        x = v / rsq; int rem = v - x * rsq; y = rem / r1; z = rem - y * r1;
        bool bx = x < R, by = y < R, bz = z < R;
        interior = bx && by && bz;
        bool inb[7] = {bz, by, by && bz, bx, bx && bz, bx && by, interior};
        int deltas[7] = {1, r1, r1 + 1, rsq, rsq + 1, rsq + r1, rsq + r1 + 1};
        int ob = occv ? 1 : 0;
        for (int j = 0; j < 7; j++) {
            float l = inb[j] ? level[v + deltas[j]] : 0.f;
            lb[j] = l;
            bool o = inb[j] && (l > 0.f);
            ob |= (o ? 1 : 0) << (j + 1);
            if (inb[j] && (o != occv)) flags |= 1 << j;
        }
        if (interior) {
            cidx = ((x * R) + y) * R + z;
            obByte[cidx] = (unsigned char)ob;
            for (int k = 0; k < 6; k++) {
                int ti = ((ob >> c_tc[k][0]) & 1) | (((ob >> c_tc[k][1]) & 1) << 1)
                       | (((ob >> c_tc[k][2]) & 1) << 2) | (((ob >> c_tc[k][3]) & 1) << 3);
                int n = c_num_tri[ti];
                n1 += (n == 1); n2 += (n == 2);
            }
        }
    }
    int cnt = __popc(flags);
    int pk = n1 | (n2 << 16);
    int lane = threadIdx.x & 63, wv = threadIdx.x >> 6;
    int inclE = cnt, inclT = pk;
    for (int o = 1; o < 64; o <<= 1) {
        int tE = __shfl_up(inclE, o);
        int tT = __shfl_up(inclT, o);
        if (lane >= o) { inclE += tE; inclT += tT; }
    }
    __shared__ int wE[4], wT[4];
    __shared__ ull sExcl;
    if (lane == 63) { wE[wv] = inclE; wT[wv] = inclT; }
    __syncthreads();

    if (wv == 0) {
        int eb = 0, t1b = 0, t2b = 0;
        if (lane == 0) {
            eb = wE[0] + wE[1] + wE[2] + wE[3];
            int tb = wT[0] + wT[1] + wT[2] + wT[3];
            t1b = tb & 0xffff; t2b = tb >> 16;
            ST_ST(&stateA[b], (1ull << 63) | ((ull)eb << 42) | ((ull)t1b << 21) | (ull)t2b);
        }
        ull sum = 0;
        for (int w = 0; 64 * w < b; w++) {
            int i = b - 1 - 64 * w - lane;
            ull pv = (i >= 0) ? ST_LD(&prefS[i]) : 0;
            ull pm = __ballot(i >= 0 && (pv >> 63));
            int Lp = pm ? (__ffsll((long long)pm) - 1) : 64;
            ull val = 0;
            if (i >= 0 && lane < Lp) {
                ull s;
                do { s = ST_LD(&stateA[i]); } while (!(s >> 63));
                val = s & VMASK;
            } else if (i >= 0 && lane == Lp) {
                val = pv & VMASK;
            }
            for (int o = 1; o < 64; o <<= 1) val += __shfl_xor(val, o);
            sum += val;
            if (Lp < 64) break;
        }
        if (lane == 0) {
            sExcl = sum;
            ull inc = sum + (((ull)eb << 42) | ((ull)t1b << 21) | (ull)t2b);
            ST_ST(&prefS[b], (1ull << 63) | inc);
            if (b == (int)gridDim.x - 1) {
                totals[0] = (int)((inc >> 42) & 0x1FFFFF);  // M
                totals[1] = (int)((inc >> 21) & 0x1FFFFF);  // N1
                totals[2] = (int)(inc & 0x1FFFFF);          // N2
            }
        }
    }
    __syncthreads();

    ull ex = sExcl;
    int exclE = (int)((ex >> 42) & 0x1FFFFF);
    int excl1 = (int)((ex >> 21) & 0x1FFFFF);
    int excl2 = (int)(ex & 0x1FFFFF);
    int woffE = 0, woffT = 0;
    for (int w = 0; w < wv; w++) { woffE += wE[w]; woffT += wT[w]; }
    int rank0 = exclE + woffE + inclE - cnt;
    int tExcl = woffT + inclT - pk;
    if (interior)
        cubeRank[cidx] = make_uint2((unsigned)(excl1 + (tExcl & 0xffff)),
                                    (unsigned)(excl2 + (tExcl >> 16)));

    if (valid) {
        int er[7]; int r = rank0;
        for (int j = 0; j < 7; j++) er[j] = ((flags >> j) & 1) ? r++ : -1;
        for (int j = 0; j < 7; j++) edgeRank[(size_t)j * NV + v] = er[j];  // SoA, coalesced
    }
    if (flags) {
        int deltas[7] = {1, r1, r1 + 1, rsq, rsq + 1, rsq + r1, rsq + r1 + 1};
        const int dxs[7] = {0, 0, 0, 1, 1, 1, 1};
        const int dys[7] = {0, 1, 1, 0, 0, 1, 1};
        const int dzs[7] = {1, 0, 1, 0, 1, 0, 1};
        float pax = x * invR + tanhf(deform[3 * v])     * invR;
        float pay = y * invR + tanhf(deform[3 * v + 1]) * invR;
        float paz = z * invR + tanhf(deform[3 * v + 2]) * invR;
        int r = rank0;
        for (int j = 0; j < 7; j++) {
            if (!((flags >> j) & 1)) continue;
            int bb = v + deltas[j];
            float lbv = lb[j];
            float denom = la - lbv;
            float w0 = (-lbv) / denom;
            float w1f = la / denom;
            float pbx = (x + dxs[j]) * invR + tanhf(deform[3 * bb])     * invR;
            float pby = (y + dys[j]) * invR + tanhf(deform[3 * bb + 1]) * invR;
            float pbz = (z + dzs[j]) * invR + tanhf(deform[3 * bb + 2]) * invR;
            out[3 * r]     = pax * w0 + pbx * w1f;
            out[3 * r + 1] = pay * w0 + pby * w1f;
            out[3 * r + 2] = paz * w0 + pbz * w1f;
            r++;
        }
    }
}

// K2: tet-per-thread, scan-free. tab[ob] (64-bit): per-k tet index (4b at 4k),
// per-k nt (2b at 32+2k).  (32-bit packing overflowed for k>=4 — R4 bug.)
__global__ void k_face(int NV, int r1, int NT,
                       const unsigned char* __restrict__ obByte,
                       const uint2* __restrict__ cubeRank,
                       const int* __restrict__ edgeRank, const int* __restrict__ totals,
                       float* __restrict__ out) {
    __shared__ ull tab[256];
    if (threadIdx.x < 256) {
        int ob = threadIdx.x;
        ull w = 0;
        for (int k = 0; k < 6; k++) {
            int ti = ((ob >> c_tc[k][0]) & 1) | (((ob >> c_tc[k][1]) & 1) << 1)
                   | (((ob >> c_tc[k][2]) & 1) << 2) | (((ob >> c_tc[k][3]) & 1) << 3);
            w |= (ull)ti << (4 * k);
            w |= (ull)c_num_tri[ti] << (32 + 2 * k);
        }
        tab[ob] = w;
    }
    __syncthreads();

    int t = blockIdx.x * 256 + threadIdx.x;
    if (t >= NT) return;
    int c = t / 6;
    int k = t - c * 6;
    int ob = obByte[c];
    ull w = tab[ob];
    int nt = (int)(w >> (32 + 2 * k)) & 3;
    if (nt == 0) return;
    int ti = (int)(w >> (4 * k)) & 15;
    int pre1 = 0, pre2 = 0;
    for (int kk = 0; kk < k; kk++) {
        int m = (int)(w >> (32 + 2 * kk)) & 3;
        pre1 += (m == 1); pre2 += (m == 2);
    }
    uint2 cr = cubeRank[c];
    int R = r1 - 1, rsq = r1 * r1;
    int rr = R * R;
    int cx = c / rr; int rem = c - cx * rr; int cy = rem / R; int cz = rem - cy * R;
    int v = (cx * r1 + cy) * r1 + cz;

    int M = totals[0], N1 = totals[1];
    float* faces = out + 3 * (size_t)M;
    int off[8] = {0, 1, r1, r1 + 1, rsq, rsq + 1, rsq + r1, rsq + r1 + 1};
    int ne = nt * 3;
    float vals[6];
    for (int e = 0; e < ne; e++) {
        int le = c_tri_tab[ti][e];
        int ce = c_te[k][le];
        int a = v + off[ce >> 3];
        vals[e] = (float)edgeRank[(size_t)(ce & 7) * NV + a];
    }
    if (nt == 1) {
        size_t base = 3 * (size_t)(cr.x + pre1);
        faces[base] = vals[0]; faces[base + 1] = vals[1]; faces[base + 2] = vals[2];
    } else {
        size_t base = 3 * ((size_t)N1 + 2 * (size_t)(cr.y + pre2));
        for (int e = 0; e < 6; e++) faces[base + e] = vals[e];
    }
}

extern "C" void kernel_launch(void* const* d_in, const int* in_sizes, int n_in,
                              void* d_out, int out_size, void* d_ws, size_t ws_size,
                              hipStream_t stream) {
    const float* level  = (const float*)d_in[0];
    const float* deform = (const float*)d_in[1];
    int NV = in_sizes[0];
    int r1 = 1;
    while ((long long)r1 * r1 * r1 < (long long)NV) r1++;
    int R = r1 - 1;
    float invR = 1.0f / (float)R;

    int nb = (NV + 255) / 256;
    int nw = (NV + 63) / 64;
    int NC = R * R * R;
    int NT = 6 * NC;
    int nbT = (NT + 255) / 256;

    char* w = (char*)d_ws;
    int* edgeRank = (int*)w;
    w += (((size_t)NV * 7 * sizeof(int)) + 255) & ~(size_t)255;
    ull* occ64 = (ull*)w;
    w += (((size_t)nw * 8) + 255) & ~(size_t)255;
    unsigned char* obByte = (unsigned char*)w;
    w += (((size_t)NC) + 255) & ~(size_t)255;
    uint2* cubeRank = (uint2*)w;
    w += (((size_t)NC * 8) + 255) & ~(size_t)255;
    ull* stateA = (ull*)w;
    ull* prefS = stateA + nb;
    int* totals = (int*)(prefS + nb);
    size_t zbytes = (size_t)nb * 16 + 4 * sizeof(int);

    float* out = (float*)d_out;

    hipMemsetAsync(stateA, 0, zbytes, stream);
    k_vert<<<nb, 256, 0, stream>>>(level, deform, NV, r1, invR, occ64, stateA, prefS,
                                   edgeRank, obByte, cubeRank, totals, out);
    k_face<<<nbT, 256, 0, stream>>>(NV, r1, NT, obByte, cubeRank, edgeRank, totals, out);
}